// Round 15
// baseline (209.636 us; speedup 1.0000x reference)
//
#include <hip/hip_runtime.h>
#include <math.h>

#define BN    16
#define NGTC  32
#define NB    2048      // 11-bit value buckets: float_bits >> 21
#define BSH   21
#define BLK   256
#define GX    128       // k_main blocks per batch row
#define CNTSH 42        // count field shift in packed u64 histogram
#define FPS   524288.0f // 2^19 fixed-point scale for packed sum

struct Accum {
  unsigned int npos[BN];
  float pos_sum;
  float box_sum;
  unsigned int counter;     // k_post 16-block ticket
  unsigned int rw_np[BN];   // per-row corrected n_pos (k_post)
  float rw_hard[BN];        // per-row hard-negative sum (k_post)
};

__device__ inline float wred_sum_f(float v) {
#pragma unroll
  for (int o = 32; o > 0; o >>= 1) v += __shfl_down(v, o, 64);
  return v;
}
__device__ inline unsigned wred_sum_u(unsigned v) {
#pragma unroll
  for (int o = 32; o > 0; o >>= 1) v += __shfl_down(v, o, 64);
  return v;
}
__device__ inline float sl1(float d) {
  float ad = fabsf(d);
  return ad < 1.f ? 0.5f * d * d : ad - 0.5f;
}
// Same code in k_main and k_post so correction swaps cancel bit-exactly.
__device__ inline float boxterm(float4 av, float4 g, float4 p) {
  float acx = (av.x + av.z) * 0.5f, acy = (av.y + av.w) * 0.5f;
  float aw = av.z - av.x, ah = av.w - av.y;
  float gcx = (g.x + g.z) * 0.5f, gcy = (g.y + g.w) * 0.5f;
  float gw = g.z - g.x, gh = g.w - g.y;
  float t0 = (gcx - acx) / (aw / 10.f);
  float t1 = (gcy - acy) / (ah / 10.f);
  float t2 = __logf(gw / aw) * 5.f;
  float t3 = __logf(gh / ah) * 5.f;
  return sl1(p.x - t0) + sl1(p.y - t1) + sl1(p.z - t2) + sl1(p.w - t3);
}
// Agent-scope loads (k_post cross-block final combine, same kernel).
__device__ inline unsigned aload_u(const unsigned* p) {
  return __hip_atomic_load(p, __ATOMIC_RELAXED, __HIP_MEMORY_SCOPE_AGENT);
}
__device__ inline float aload_f(const float* p) {
  return __hip_atomic_load(p, __ATOMIC_RELAXED, __HIP_MEMORY_SCOPE_AGENT);
}

// Fused main pass. Measured lessons:
//  (R4)  no min-waves in launch_bounds (VGPR cap -> scratch spills).
//  (R5)  no read-guard on ds atomics; cap unroll (full unroll -> 176 VGPR).
//  (R9)  fold the 2 anchors' per-GT candidates -> ONE key per jj.
//  (R12) no register-array key batching (keys[8] u64 -> 224 VGPR, 9% occ).
//  (R13) occupancy supply (4 vs 8 blocks/CU): null.
//  (R14) shfl butterfly = ds_bpermute = MORE LDS-pipe work: -50%. Atomic
//        COUNT also null (R6 2/jj == R11 1/jj). R15 test: GT boxes read from
//        GLOBAL (L2, vmcnt queue) with uniform j -> the j-loop issues ZERO
//        lgkmcnt-queued reads; VALU no longer waits behind the in-order
//        ds_atomic stream. Broadcast load = 1 L2 request per wave per j.
__global__ __launch_bounds__(BLK) void k_main(
    const float* __restrict__ labels, const float4* __restrict__ poffs,
    const float4* __restrict__ anchors, const float4* __restrict__ gt,
    Accum* __restrict__ acc, unsigned long long* __restrict__ partial,
    unsigned long long* __restrict__ ghist, int A) {
  __shared__ unsigned long long hist[NB];   // (count<<42) | fixedpoint-sum
  __shared__ unsigned long long sbest[NGTC];
  __shared__ float sredf[BLK / 64], sredb[BLK / 64];
  __shared__ unsigned sredu[BLK / 64];
  int b = blockIdx.y, t = threadIdx.x;
  const float4* __restrict__ gtrow = gt + b * NGTC;
  for (int i = t; i < NB; i += BLK) hist[i] = 0ull;
  if (t < NGTC) sbest[t] = 0ull;
  __syncthreads();

  float psum = 0.f, bsum = 0.f;
  unsigned cnt = 0u;
  for (int a0 = blockIdx.x * (2 * BLK) + t; a0 < A; a0 += GX * 2 * BLK) {
    int a1 = a0 + BLK;
    bool v1 = a1 < A;
    float4 av0 = anchors[a0];
    // invalid -> degenerate far box: inter==0 with every gt
    float4 av1 = v1 ? anchors[a1] : make_float4(2.f, 2.f, 2.f, 2.f);
    float area0 = (av0.z - av0.x) * (av0.w - av0.y);
    float area1 = (av1.z - av1.x) * (av1.w - av1.y);
    unsigned na0 = ~(unsigned)a0, na1 = ~(unsigned)a1;
    float bn0 = -1.f, bd0 = 1.f, bn1 = -1.f, bd1 = 1.f;
    int gid0 = 0, gid1 = 0;
#pragma unroll 8
    for (int j = 0; j < NGTC; ++j) {    // uniform j: broadcast L2 load
      float4 g = gtrow[j];              // vmcnt queue, NOT lgkmcnt (R15)
      float ga = (g.z - g.x) * (g.w - g.y);
      float w0 = fmaxf(fminf(av0.z, g.z) - fmaxf(av0.x, g.x), 0.f);
      float h0 = fmaxf(fminf(av0.w, g.w) - fmaxf(av0.y, g.y), 0.f);
      float i0 = w0 * h0;
      float d0 = area0 + ga - i0;
      if (i0 * bd0 > bn0 * d0) { bn0 = i0; bd0 = d0; gid0 = j; }
      float w1 = fmaxf(fminf(av1.z, g.z) - fmaxf(av1.x, g.x), 0.f);
      float h1 = fmaxf(fminf(av1.w, g.w) - fmaxf(av1.y, g.y), 0.f);
      float i1 = w1 * h1;
      float d1 = area1 + ga - i1;
      if (i1 * bd1 > bn1 * d1) { bn1 = i1; bd1 = d1; gid1 = j; }
      // fold the two candidates exactly (i1/d1 > i0/d0 <=> i1*d0 > i0*d1;
      // strict > keeps a0 = smaller index on ties, matching first-argmax)
      bool take1 = i1 * d0 > i0 * d1;
      float iw = take1 ? i1 : i0;
      float dw = take1 ? d1 : d0;
      unsigned naw = take1 ? na1 : na0;
      if (iw > 0.f) {
        float iou = iw * __builtin_amdgcn_rcpf(dw);  // ordering key only
        atomicMax(&sbest[j],
                  (((unsigned long long)__float_as_uint(iou)) << 32) | naw);
      }
    }
#pragma unroll
    for (int q = 0; q < 2; ++q) {
      int a = q ? a1 : a0;
      if (q && !v1) break;
      float4 av = q ? av1 : av0;
      float bn = q ? bn1 : bn0, bd = q ? bd1 : bd0;
      int gid = q ? gid1 : gid0;
      bool pos = bn > 0.3f * bd;
      float x = labels[(size_t)b * A + a];
      float e = __expf(-fabsf(x));
      float sp = fmaxf(x, 0.f) + __logf(1.f + e);   // softplus = bce(y=0)
      if (pos) {
        cnt++; psum += sp - x;                       // bce(y=1)
        float4 p = poffs[(size_t)b * A + a];
        bsum += boxterm(av, gtrow[gid], p);
      } else {
        unsigned bk = __float_as_uint(sp) >> BSH;
        atomicAdd(&hist[bk],
                  (1ull << CNTSH) + (unsigned long long)(unsigned)(sp * FPS + 0.5f));
      }
    }
  }
  __syncthreads();
  if (t < NGTC)
    partial[(size_t)blockIdx.x * (BN * NGTC) + b * NGTC + t] = sbest[t];

  psum = wred_sum_f(psum);
  bsum = wred_sum_f(bsum);
  cnt  = wred_sum_u(cnt);
  int wid = t >> 6, lane = t & 63;
  if (lane == 0) { sredf[wid] = psum; sredb[wid] = bsum; sredu[wid] = cnt; }
  __syncthreads();
  if (t == 0) {
    float ps = 0.f, bs = 0.f; unsigned c = 0;
#pragma unroll
    for (int w2 = 0; w2 < BLK / 64; ++w2) { ps += sredf[w2]; bs += sredb[w2]; c += sredu[w2]; }
    if (c) atomicAdd(&acc->npos[b], c);
    atomicAdd(&acc->pos_sum, ps);
    atomicAdd(&acc->box_sum, bs);
  }
  // merge nonzero buckets: ONE u64 atomic each (packed fields add independently)
  for (int i = t; i < NB; i += BLK) {
    unsigned long long pk = hist[i];
    if (pk) atomicAdd(&ghist[(size_t)b * NB + i], pk);
  }
}

// Parallel epilogue: one block per batch row. Stage+unpack histogram to LDS,
// corrections in LDS, wave-parallel suffix scan; t0 UNCONDITIONALLY does
// writeback+ticket (R10: no data-dependent gating of the ticket — when
// k >= total negatives the reference takes ALL = t0's suffix total).
__global__ __launch_bounds__(BLK) void k_post(
    const float* __restrict__ labels, const float4* __restrict__ poffs,
    const float4* __restrict__ anchors, const float4* __restrict__ gt,
    Accum* __restrict__ acc, const unsigned long long* __restrict__ partial,
    const unsigned long long* __restrict__ ghist,
    float* __restrict__ out, int A, int nbx) {
  __shared__ unsigned hc[NB];
  __shared__ float    hsum[NB];
  __shared__ unsigned long long spart[BLK];
  __shared__ unsigned sa[NGTC];
  __shared__ float sdpos, sdbox;
  __shared__ unsigned sdnp;
  __shared__ unsigned sk;                  // 3 * corrected n_pos
  __shared__ unsigned swtc[BLK / 64];      // wave suffix totals
  __shared__ float    swts[BLK / 64];
  __shared__ float    srow_hard;
  __shared__ int      sdone;
  int b = blockIdx.x, t = threadIdx.x;

  // stage + unpack row histogram (coalesced u64 loads)
  for (int i = t; i < NB; i += BLK) {
    unsigned long long pk = ghist[(size_t)b * NB + i];
    hc[i] = (unsigned)(pk >> CNTSH);
    hsum[i] = (float)(pk & ((1ull << CNTSH) - 1ull)) * (1.f / FPS);
  }
  // parallel partial-key reduce: thread (chunk=t>>5, j=t&31) covers nbx/8 blocks
  {
    int j = t & 31, ch = t >> 5;
    unsigned long long best = 0ull;
    int i0 = ch * (nbx / 8), i1 = i0 + (nbx / 8);
    for (int i = i0; i < i1; ++i) {
      unsigned long long v = partial[(size_t)i * (BN * NGTC) + b * NGTC + j];
      best = v > best ? v : best;
    }
    spart[t] = best;
  }
  if (t == 0) { sdpos = 0.f; sdbox = 0.f; sdnp = 0u; sdone = 0; }
  __syncthreads();
  if (t < NGTC) {
    unsigned long long m = spart[t];
#pragma unroll
    for (int c = 1; c < 8; ++c) {
      unsigned long long v = spart[c * 32 + t];
      m = v > m ? v : m;
    }
    if (m == 0ull) m = 0xFFFFFFFFull;  // no overlap -> anchor 0
    sa[t] = ~(unsigned)(m & 0xFFFFFFFFull);
  }
  __syncthreads();

  // forced-match corrections (threads 0..31, one per gt)
  if (t < NGTC) {
    unsigned a = sa[t];
    bool winner = true;
    for (int j2 = t + 1; j2 < NGTC; ++j2)
      if (sa[j2] == a) { winner = false; break; }  // last j wins
    if (winner) {
      // Replicate k_main's per-anchor pass EXACTLY (uniform j order 0..31).
      float4 avx = anchors[a];
      float area_a = (avx.z - avx.x) * (avx.w - avx.y);
      float bn = -1.f, bd = 1.f;
      int gid = 0;
      for (int j2 = 0; j2 < NGTC; ++j2) {
        float4 g = gt[b * NGTC + j2];
        float ga = (g.z - g.x) * (g.w - g.y);
        float w = fmaxf(fminf(avx.z, g.z) - fmaxf(avx.x, g.x), 0.f);
        float h = fmaxf(fminf(avx.w, g.w) - fmaxf(avx.y, g.y), 0.f);
        float inter = w * h;
        float dj = area_a + ga - inter;
        if (inter * bd > bn * dj) { bn = inter; bd = dj; gid = j2; }
      }
      bool tpos = bn > 0.3f * bd;
      float4 p4 = poffs[(size_t)b * A + a];
      float newbox = boxterm(avx, gt[b * NGTC + t], p4);
      if (tpos) {
        if (gid != t) {   // box target overridden: swap terms
          float oldbox = boxterm(avx, gt[b * NGTC + gid], p4);
          atomicAdd(&sdbox, newbox - oldbox);
        }
      } else {            // was counted negative: promote to positive
        float x = labels[(size_t)b * A + a];
        float e = __expf(-fabsf(x));
        float sp = fmaxf(x, 0.f) + __logf(1.f + e);
        atomicAdd(&sdnp, 1u);
        atomicAdd(&sdpos, sp - x);
        atomicAdd(&sdbox, newbox);
        unsigned bk = __float_as_uint(sp) >> BSH;
        atomicSub(&hc[bk], 1u);
        atomicAdd(&hsum[bk], -sp);
      }
    }
  }
  __syncthreads();
  if (t == 0) sk = 3u * (acc->npos[b] + sdnp);

  // per-thread chunk sums (8 buckets each) in registers
  unsigned cth = 0; float sth = 0.f;
  {
    int base = t * (NB / BLK);
#pragma unroll
    for (int i = 0; i < NB / BLK; ++i) { cth += hc[base + i]; sth += hsum[base + i]; }
  }
  // wave-internal suffix-inclusive scan (descending index)
  int lane = t & 63, wv = t >> 6;
  unsigned S = cth; float Sf = sth;
#pragma unroll
  for (int off = 1; off < 64; off <<= 1) {
    unsigned cn = __shfl_down(S, off, 64);
    float sn = __shfl_down(Sf, off, 64);
    if (lane + off < 64) { S += cn; Sf += sn; }
  }
  if (lane == 0) { swtc[wv] = S; swts[wv] = Sf; }  // wave totals
  __syncthreads();
#pragma unroll
  for (int w2 = 0; w2 < BLK / 64; ++w2)
    if (w2 > wv) { S += swtc[w2]; Sf += swts[w2]; }
  // S/Sf for thread t = suffix over threads t..255; t0 holds the TOTAL.

  // boundary thread (unique when 1 <= k <= total): compute hard, hand off
  unsigned k = sk;
  if (k > 0u && S >= k && S - cth < k) {
    unsigned cum = S - cth;          // count strictly above my chunk
    float hard = Sf - sth;           // sum strictly above my chunk
    int base = t * (NB / BLK);
    for (int u = NB / BLK - 1; u >= 0; --u) {
      int bk = base + u;
      unsigned c2 = hc[bk];
      if (cum + c2 >= k) {
        unsigned r = k - cum;
        if (c2 && r) {
          float m  = hsum[bk] / (float)c2;
          float lo = __uint_as_float((unsigned)bk << BSH);
          float hi = __uint_as_float((unsigned)(bk + 1) << BSH);
          // uniform-within-bucket model; exact at r==c2
          hard += (float)r * m +
                  (float)r * (float)(c2 - r) * (hi - lo) / (2.f * (float)c2);
        }
        break;
      }
      cum += c2; hard += hsum[bk];
    }
    srow_hard = hard;
    sdone = 1;
  }
  __syncthreads();

  // t0 ALWAYS writes back and tickets (fallback: k >= total -> take all)
  if (t == 0) {
    float hard = sdone ? srow_hard : Sf;   // t0's Sf == total negative sum
    acc->rw_np[b] = k / 3u;
    acc->rw_hard[b] = hard;
    atomicAdd(&acc->pos_sum, sdpos);
    atomicAdd(&acc->box_sum, sdbox);
    __threadfence();
    unsigned tk = atomicAdd(&acc->counter, 1u);
    if (tk == BN - 1u) {       // last row block: final combine
      __threadfence();
      unsigned npt = 0; float hardt = 0.f;
      for (int bb = 0; bb < BN; ++bb) {
        npt += aload_u(&acc->rw_np[bb]);
        hardt += aload_f(&acc->rw_hard[bb]);
      }
      float npf = (float)npt;
      float box = aload_f(&acc->box_sum) / (npf * 4.f);
      float cls = (hardt + aload_f(&acc->pos_sum)) / npf;
      out[0] = box + cls;
      out[1] = box;
      out[2] = cls;
    }
  }
}

extern "C" void kernel_launch(void* const* d_in, const int* in_sizes, int n_in,
                              void* d_out, int out_size, void* d_ws, size_t ws_size,
                              hipStream_t stream) {
  const float*  labels  = (const float*)d_in[0];
  const float4* poffs   = (const float4*)d_in[1];
  const float4* anchors = (const float4*)d_in[2];
  const float4* gt      = (const float4*)d_in[3];
  int A = in_sizes[2] / 4;  // 100000

  char* ws = (char*)d_ws;
  Accum* acc = (Accum*)ws;
  size_t off_gh = (sizeof(Accum) + 255) & ~(size_t)255;
  unsigned long long* ghist = (unsigned long long*)(ws + off_gh);
  size_t off_part = off_gh + (size_t)BN * NB * sizeof(unsigned long long);
  unsigned long long* partial = (unsigned long long*)(ws + off_part);
  // partial (GX*512 u64) is fully written by k_main each call; no memset.

  hipMemsetAsync(ws, 0, off_part, stream);  // Accum(+ticket+rowres) + ghist

  dim3 grid(GX, BN);
  k_main<<<grid, BLK, 0, stream>>>(labels, poffs, anchors, gt, acc, partial,
                                   ghist, A);
  k_post<<<BN, BLK, 0, stream>>>(labels, poffs, anchors, gt, acc, partial,
                                 ghist, (float*)d_out, A, GX);
}

// Round 16
// 85.326 us; speedup vs baseline: 2.4569x; 2.4569x over previous
//
#include <hip/hip_runtime.h>
#include <math.h>

#define BN    16
#define NGTC  32
#define NB    1024      // 10-bit value buckets: float_bits >> 22
#define BSH   22
#define BLK   256
#define GX    64        // k_main blocks per batch row
#define CNTSH 42        // count field shift in packed u64 histogram
#define FPS   524288.0f // 2^19 fixed-point scale for packed sum

struct Accum {
  unsigned int npos[BN];
  float pos_sum;
  float box_sum;
  unsigned int counter;     // k_post 16-block ticket
  unsigned int rw_np[BN];   // per-row corrected n_pos (k_post)
  float rw_hard[BN];        // per-row hard-negative sum (k_post)
};

__device__ inline float wred_sum_f(float v) {
#pragma unroll
  for (int o = 32; o > 0; o >>= 1) v += __shfl_down(v, o, 64);
  return v;
}
__device__ inline unsigned wred_sum_u(unsigned v) {
#pragma unroll
  for (int o = 32; o > 0; o >>= 1) v += __shfl_down(v, o, 64);
  return v;
}
__device__ inline float sl1(float d) {
  float ad = fabsf(d);
  return ad < 1.f ? 0.5f * d * d : ad - 0.5f;
}
// Same code in k_main and k_post so correction swaps cancel bit-exactly.
__device__ inline float boxterm(float4 av, float4 g, float4 p) {
  float acx = (av.x + av.z) * 0.5f, acy = (av.y + av.w) * 0.5f;
  float aw = av.z - av.x, ah = av.w - av.y;
  float gcx = (g.x + g.z) * 0.5f, gcy = (g.y + g.w) * 0.5f;
  float gw = g.z - g.x, gh = g.w - g.y;
  float t0 = (gcx - acx) / (aw / 10.f);
  float t1 = (gcy - acy) / (ah / 10.f);
  float t2 = __logf(gw / aw) * 5.f;
  float t3 = __logf(gh / ah) * 5.f;
  return sl1(p.x - t0) + sl1(p.y - t1) + sl1(p.z - t2) + sl1(p.w - t3);
}
// Agent-scope loads (k_post cross-block final combine, same kernel).
__device__ inline unsigned aload_u(const unsigned* p) {
  return __hip_atomic_load(p, __ATOMIC_RELAXED, __HIP_MEMORY_SCOPE_AGENT);
}
__device__ inline float aload_f(const float* p) {
  return __hip_atomic_load(p, __ATOMIC_RELAXED, __HIP_MEMORY_SCOPE_AGENT);
}

// Fused main pass. Measured lessons:
//  (R4)  no min-waves in launch_bounds (VGPR cap -> scratch spills).
//  (R5)  no read-guard on ds atomics; cap unroll (full unroll -> 176 VGPR).
//  (R9)  fold the 2 anchors' per-GT candidates -> ONE key per jj.
//  (R12) no register-array key batching (keys[8] u64 -> 224 VGPR, 9% occ).
//  (R13) occupancy supply: null. (R14) shfl butterfly = ds_bpermute = worse.
//  (R15) global GT reads (vmcnt) = much worse; LDS reads were fine.
//  (R16) SoA sgt: the AoS float4[32] read at 16B stride was an 8-way bank
//        conflict (lane l -> banks 4l..4l+3 mod 32); SoA b32 reads at 4B
//        stride are conflict-free. Values/op-order bit-identical to R13.
__global__ __launch_bounds__(BLK) void k_main(
    const float* __restrict__ labels, const float4* __restrict__ poffs,
    const float4* __restrict__ anchors, const float4* __restrict__ gt,
    Accum* __restrict__ acc, unsigned long long* __restrict__ partial,
    unsigned long long* __restrict__ ghist, int A) {
  __shared__ unsigned long long hist[NB];   // (count<<42) | fixedpoint-sum
  __shared__ unsigned long long sbest[NGTC];
  __shared__ float sgx[NGTC], sgy[NGTC], sgz[NGTC], sgw[NGTC];  // SoA (R16)
  __shared__ float sredf[BLK / 64], sredb[BLK / 64];
  __shared__ unsigned sredu[BLK / 64];
  int b = blockIdx.y, t = threadIdx.x;
  for (int i = t; i < NB; i += BLK) hist[i] = 0ull;
  if (t < NGTC) {
    float4 g = gt[b * NGTC + t];
    sgx[t] = g.x; sgy[t] = g.y; sgz[t] = g.z; sgw[t] = g.w;
    sbest[t] = 0ull;
  }
  __syncthreads();

  float psum = 0.f, bsum = 0.f;
  unsigned cnt = 0u;
  int rot = t & 31;
  for (int a0 = blockIdx.x * (2 * BLK) + t; a0 < A; a0 += GX * 2 * BLK) {
    int a1 = a0 + BLK;
    bool v1 = a1 < A;
    float4 av0 = anchors[a0];
    // invalid -> degenerate far box: inter==0 with every gt
    float4 av1 = v1 ? anchors[a1] : make_float4(2.f, 2.f, 2.f, 2.f);
    float area0 = (av0.z - av0.x) * (av0.w - av0.y);
    float area1 = (av1.z - av1.x) * (av1.w - av1.y);
    unsigned na0 = ~(unsigned)a0, na1 = ~(unsigned)a1;
    float bn0 = -1.f, bd0 = 1.f, bn1 = -1.f, bd1 = 1.f;
    int gid0 = 0, gid1 = 0;
#pragma unroll 8
    for (int jj = 0; jj < NGTC; ++jj) {
      int j = (jj + rot) & 31;    // stagger lanes across the 32 sbest slots
      float4 g = make_float4(sgx[j], sgy[j], sgz[j], sgw[j]);  // conflict-free
      float ga = (g.z - g.x) * (g.w - g.y);
      float w0 = fmaxf(fminf(av0.z, g.z) - fmaxf(av0.x, g.x), 0.f);
      float h0 = fmaxf(fminf(av0.w, g.w) - fmaxf(av0.y, g.y), 0.f);
      float i0 = w0 * h0;
      float d0 = area0 + ga - i0;
      if (i0 * bd0 > bn0 * d0) { bn0 = i0; bd0 = d0; gid0 = j; }
      float w1 = fmaxf(fminf(av1.z, g.z) - fmaxf(av1.x, g.x), 0.f);
      float h1 = fmaxf(fminf(av1.w, g.w) - fmaxf(av1.y, g.y), 0.f);
      float i1 = w1 * h1;
      float d1 = area1 + ga - i1;
      if (i1 * bd1 > bn1 * d1) { bn1 = i1; bd1 = d1; gid1 = j; }
      // fold the two candidates exactly (i1/d1 > i0/d0 <=> i1*d0 > i0*d1;
      // strict > keeps a0 = smaller index on ties, matching first-argmax)
      bool take1 = i1 * d0 > i0 * d1;
      float iw = take1 ? i1 : i0;
      float dw = take1 ? d1 : d0;
      unsigned naw = take1 ? na1 : na0;
      if (iw > 0.f) {
        float iou = iw * __builtin_amdgcn_rcpf(dw);  // ordering key only
        atomicMax(&sbest[j],
                  (((unsigned long long)__float_as_uint(iou)) << 32) | naw);
      }
    }
#pragma unroll
    for (int q = 0; q < 2; ++q) {
      int a = q ? a1 : a0;
      if (q && !v1) break;
      float4 av = q ? av1 : av0;
      float bn = q ? bn1 : bn0, bd = q ? bd1 : bd0;
      int gid = q ? gid1 : gid0;
      bool pos = bn > 0.3f * bd;
      float x = labels[(size_t)b * A + a];
      float e = __expf(-fabsf(x));
      float sp = fmaxf(x, 0.f) + __logf(1.f + e);   // softplus = bce(y=0)
      if (pos) {
        cnt++; psum += sp - x;                       // bce(y=1)
        float4 p = poffs[(size_t)b * A + a];
        float4 g = make_float4(sgx[gid], sgy[gid], sgz[gid], sgw[gid]);
        bsum += boxterm(av, g, p);
      } else {
        unsigned bk = __float_as_uint(sp) >> BSH;
        atomicAdd(&hist[bk],
                  (1ull << CNTSH) + (unsigned long long)(unsigned)(sp * FPS + 0.5f));
      }
    }
  }
  __syncthreads();
  if (t < NGTC)
    partial[(size_t)blockIdx.x * (BN * NGTC) + b * NGTC + t] = sbest[t];

  psum = wred_sum_f(psum);
  bsum = wred_sum_f(bsum);
  cnt  = wred_sum_u(cnt);
  int wid = t >> 6, lane = t & 63;
  if (lane == 0) { sredf[wid] = psum; sredb[wid] = bsum; sredu[wid] = cnt; }
  __syncthreads();
  if (t == 0) {
    float ps = 0.f, bs = 0.f; unsigned c = 0;
#pragma unroll
    for (int w2 = 0; w2 < BLK / 64; ++w2) { ps += sredf[w2]; bs += sredb[w2]; c += sredu[w2]; }
    if (c) atomicAdd(&acc->npos[b], c);
    atomicAdd(&acc->pos_sum, ps);
    atomicAdd(&acc->box_sum, bs);
  }
  // merge nonzero buckets: ONE u64 atomic each (packed fields add independently)
  for (int i = t; i < NB; i += BLK) {
    unsigned long long pk = hist[i];
    if (pk) atomicAdd(&ghist[(size_t)b * NB + i], pk);
  }
}

// Parallel epilogue: one block per batch row. Stage+unpack histogram to LDS,
// corrections in LDS, wave-parallel suffix scan; t0 UNCONDITIONALLY does
// writeback+ticket (R10: no data-dependent gating of the ticket — when
// k >= total negatives the reference takes ALL = t0's suffix total).
__global__ __launch_bounds__(BLK) void k_post(
    const float* __restrict__ labels, const float4* __restrict__ poffs,
    const float4* __restrict__ anchors, const float4* __restrict__ gt,
    Accum* __restrict__ acc, const unsigned long long* __restrict__ partial,
    const unsigned long long* __restrict__ ghist,
    float* __restrict__ out, int A, int nbx) {
  __shared__ unsigned hc[NB];
  __shared__ float    hsum[NB];
  __shared__ unsigned long long spart[BLK];
  __shared__ unsigned sa[NGTC];
  __shared__ float sdpos, sdbox;
  __shared__ unsigned sdnp;
  __shared__ unsigned sk;                  // 3 * corrected n_pos
  __shared__ unsigned swtc[BLK / 64];      // wave suffix totals
  __shared__ float    swts[BLK / 64];
  __shared__ float    srow_hard;
  __shared__ int      sdone;
  int b = blockIdx.x, t = threadIdx.x;

  // stage + unpack row histogram (coalesced u64 loads)
  for (int i = t; i < NB; i += BLK) {
    unsigned long long pk = ghist[(size_t)b * NB + i];
    hc[i] = (unsigned)(pk >> CNTSH);
    hsum[i] = (float)(pk & ((1ull << CNTSH) - 1ull)) * (1.f / FPS);
  }
  // parallel partial-key reduce: thread (chunk=t>>5, j=t&31) covers nbx/8 blocks
  {
    int j = t & 31, ch = t >> 5;
    unsigned long long best = 0ull;
    int i0 = ch * (nbx / 8), i1 = i0 + (nbx / 8);
    for (int i = i0; i < i1; ++i) {
      unsigned long long v = partial[(size_t)i * (BN * NGTC) + b * NGTC + j];
      best = v > best ? v : best;
    }
    spart[t] = best;
  }
  if (t == 0) { sdpos = 0.f; sdbox = 0.f; sdnp = 0u; sdone = 0; }
  __syncthreads();
  if (t < NGTC) {
    unsigned long long m = spart[t];
#pragma unroll
    for (int c = 1; c < 8; ++c) {
      unsigned long long v = spart[c * 32 + t];
      m = v > m ? v : m;
    }
    if (m == 0ull) m = 0xFFFFFFFFull;  // no overlap -> anchor 0
    sa[t] = ~(unsigned)(m & 0xFFFFFFFFull);
  }
  __syncthreads();

  // forced-match corrections (threads 0..31, one per gt)
  if (t < NGTC) {
    unsigned a = sa[t];
    bool winner = true;
    for (int j2 = t + 1; j2 < NGTC; ++j2)
      if (sa[j2] == a) { winner = false; break; }  // last j wins
    if (winner) {
      // Replicate k_main's per-anchor pass EXACTLY (same rot, same op order).
      float4 avx = anchors[a];
      float area_a = (avx.z - avx.x) * (avx.w - avx.y);
      int rot = (int)(a & 31u);   // a == t (mod 256) in k_main, ILP stride 256
      float bn = -1.f, bd = 1.f;
      int gid = 0;
      for (int jj = 0; jj < NGTC; ++jj) {
        int j2 = (jj + rot) & 31;
        float4 g = gt[b * NGTC + j2];
        float ga = (g.z - g.x) * (g.w - g.y);
        float w = fmaxf(fminf(avx.z, g.z) - fmaxf(avx.x, g.x), 0.f);
        float h = fmaxf(fminf(avx.w, g.w) - fmaxf(avx.y, g.y), 0.f);
        float inter = w * h;
        float dj = area_a + ga - inter;
        if (inter * bd > bn * dj) { bn = inter; bd = dj; gid = j2; }
      }
      bool tpos = bn > 0.3f * bd;
      float4 p4 = poffs[(size_t)b * A + a];
      float newbox = boxterm(avx, gt[b * NGTC + t], p4);
      if (tpos) {
        if (gid != t) {   // box target overridden: swap terms
          float oldbox = boxterm(avx, gt[b * NGTC + gid], p4);
          atomicAdd(&sdbox, newbox - oldbox);
        }
      } else {            // was counted negative: promote to positive
        float x = labels[(size_t)b * A + a];
        float e = __expf(-fabsf(x));
        float sp = fmaxf(x, 0.f) + __logf(1.f + e);
        atomicAdd(&sdnp, 1u);
        atomicAdd(&sdpos, sp - x);
        atomicAdd(&sdbox, newbox);
        unsigned bk = __float_as_uint(sp) >> BSH;
        atomicSub(&hc[bk], 1u);
        atomicAdd(&hsum[bk], -sp);
      }
    }
  }
  __syncthreads();
  if (t == 0) sk = 3u * (acc->npos[b] + sdnp);

  // per-thread chunk sums (4 buckets each) in registers
  unsigned cth = 0; float sth = 0.f;
  {
    int base = t * (NB / BLK);
#pragma unroll
    for (int i = 0; i < NB / BLK; ++i) { cth += hc[base + i]; sth += hsum[base + i]; }
  }
  // wave-internal suffix-inclusive scan (descending index)
  int lane = t & 63, wv = t >> 6;
  unsigned S = cth; float Sf = sth;
#pragma unroll
  for (int off = 1; off < 64; off <<= 1) {
    unsigned cn = __shfl_down(S, off, 64);
    float sn = __shfl_down(Sf, off, 64);
    if (lane + off < 64) { S += cn; Sf += sn; }
  }
  if (lane == 0) { swtc[wv] = S; swts[wv] = Sf; }  // wave totals
  __syncthreads();
#pragma unroll
  for (int w2 = 0; w2 < BLK / 64; ++w2)
    if (w2 > wv) { S += swtc[w2]; Sf += swts[w2]; }
  // S/Sf for thread t = suffix over threads t..255; t0 holds the TOTAL.

  // boundary thread (unique when 1 <= k <= total): compute hard, hand off
  unsigned k = sk;
  if (k > 0u && S >= k && S - cth < k) {
    unsigned cum = S - cth;          // count strictly above my chunk
    float hard = Sf - sth;           // sum strictly above my chunk
    int base = t * (NB / BLK);
    for (int u = NB / BLK - 1; u >= 0; --u) {
      int bk = base + u;
      unsigned c2 = hc[bk];
      if (cum + c2 >= k) {
        unsigned r = k - cum;
        if (c2 && r) {
          float m  = hsum[bk] / (float)c2;
          float lo = __uint_as_float((unsigned)bk << BSH);
          float hi = __uint_as_float((unsigned)(bk + 1) << BSH);
          // uniform-within-bucket model; exact at r==c2
          hard += (float)r * m +
                  (float)r * (float)(c2 - r) * (hi - lo) / (2.f * (float)c2);
        }
        break;
      }
      cum += c2; hard += hsum[bk];
    }
    srow_hard = hard;
    sdone = 1;
  }
  __syncthreads();

  // t0 ALWAYS writes back and tickets (fallback: k >= total -> take all)
  if (t == 0) {
    float hard = sdone ? srow_hard : Sf;   // t0's Sf == total negative sum
    acc->rw_np[b] = k / 3u;
    acc->rw_hard[b] = hard;
    atomicAdd(&acc->pos_sum, sdpos);
    atomicAdd(&acc->box_sum, sdbox);
    __threadfence();
    unsigned tk = atomicAdd(&acc->counter, 1u);
    if (tk == BN - 1u) {       // last row block: final combine
      __threadfence();
      unsigned npt = 0; float hardt = 0.f;
      for (int bb = 0; bb < BN; ++bb) {
        npt += aload_u(&acc->rw_np[bb]);
        hardt += aload_f(&acc->rw_hard[bb]);
      }
      float npf = (float)npt;
      float box = aload_f(&acc->box_sum) / (npf * 4.f);
      float cls = (hardt + aload_f(&acc->pos_sum)) / npf;
      out[0] = box + cls;
      out[1] = box;
      out[2] = cls;
    }
  }
}

extern "C" void kernel_launch(void* const* d_in, const int* in_sizes, int n_in,
                              void* d_out, int out_size, void* d_ws, size_t ws_size,
                              hipStream_t stream) {
  const float*  labels  = (const float*)d_in[0];
  const float4* poffs   = (const float4*)d_in[1];
  const float4* anchors = (const float4*)d_in[2];
  const float4* gt      = (const float4*)d_in[3];
  int A = in_sizes[2] / 4;  // 100000

  char* ws = (char*)d_ws;
  Accum* acc = (Accum*)ws;
  size_t off_gh = (sizeof(Accum) + 255) & ~(size_t)255;
  unsigned long long* ghist = (unsigned long long*)(ws + off_gh);
  size_t off_part = off_gh + (size_t)BN * NB * sizeof(unsigned long long);
  unsigned long long* partial = (unsigned long long*)(ws + off_part);
  // partial (GX*512 u64) is fully written by k_main each call; no memset.

  hipMemsetAsync(ws, 0, off_part, stream);  // Accum(+ticket+rowres) + ghist (~128KB)

  dim3 grid(GX, BN);
  k_main<<<grid, BLK, 0, stream>>>(labels, poffs, anchors, gt, acc, partial,
                                   ghist, A);
  k_post<<<BN, BLK, 0, stream>>>(labels, poffs, anchors, gt, acc, partial,
                                 ghist, (float*)d_out, A, GX);
}

// Round 17
// 81.882 us; speedup vs baseline: 2.5602x; 1.0421x over previous
//
#include <hip/hip_runtime.h>
#include <math.h>

#define BN    16
#define NGTC  32
#define NB    1024      // 10-bit value buckets: float_bits >> 22
#define BSH   22
#define BLK   256
#define GX    64        // k_main blocks per batch row
#define CNTSH 42        // count field shift in packed u64 histogram
#define FPS   524288.0f // 2^19 fixed-point scale for packed sum

typedef float v2f __attribute__((ext_vector_type(2)));

struct Accum {
  unsigned int npos[BN];
  float pos_sum;
  float box_sum;
  unsigned int counter;     // k_post 16-block ticket
  unsigned int rw_np[BN];   // per-row corrected n_pos (k_post)
  float rw_hard[BN];        // per-row hard-negative sum (k_post)
};

__device__ inline float wred_sum_f(float v) {
#pragma unroll
  for (int o = 32; o > 0; o >>= 1) v += __shfl_down(v, o, 64);
  return v;
}
__device__ inline unsigned wred_sum_u(unsigned v) {
#pragma unroll
  for (int o = 32; o > 0; o >>= 1) v += __shfl_down(v, o, 64);
  return v;
}
__device__ inline float sl1(float d) {
  float ad = fabsf(d);
  return ad < 1.f ? 0.5f * d * d : ad - 0.5f;
}
// Same code in k_main and k_post so correction swaps cancel bit-exactly.
__device__ inline float boxterm(float4 av, float4 g, float4 p) {
  float acx = (av.x + av.z) * 0.5f, acy = (av.y + av.w) * 0.5f;
  float aw = av.z - av.x, ah = av.w - av.y;
  float gcx = (g.x + g.z) * 0.5f, gcy = (g.y + g.w) * 0.5f;
  float gw = g.z - g.x, gh = g.w - g.y;
  float t0 = (gcx - acx) / (aw / 10.f);
  float t1 = (gcy - acy) / (ah / 10.f);
  float t2 = __logf(gw / aw) * 5.f;
  float t3 = __logf(gh / ah) * 5.f;
  return sl1(p.x - t0) + sl1(p.y - t1) + sl1(p.z - t2) + sl1(p.w - t3);
}
// Agent-scope loads (k_post cross-block final combine, same kernel).
__device__ inline unsigned aload_u(const unsigned* p) {
  return __hip_atomic_load(p, __ATOMIC_RELAXED, __HIP_MEMORY_SCOPE_AGENT);
}
__device__ inline float aload_f(const float* p) {
  return __hip_atomic_load(p, __ATOMIC_RELAXED, __HIP_MEMORY_SCOPE_AGENT);
}

// Fused main pass. Measured lessons (R4/R5/R9/R12-R16 in git journal):
// k_main is VALU-ISSUE-bound (~97K cy/SIMD of VALU at 58% busy; all pipe
// theories nulled). R17: cut VALU cycles directly —
//  (a) two anchors' geometry as float2 ext-vectors -> v_pk_*_f32 packed
//      math (2 f32 ops per instr); worst case scalarizes to status quo.
//  (b) argmax via truncated monotone u32 key: um = max(um,
//      (iou_bits & ~31) | (31-j)) — 3 ops vs 6-op cndmask chain; exact
//      ties resolve to smallest j (first-wins). Pos test / argmax gain
//      <=31ulp fuzz: O(1e-3) loss delta vs 7.9e-2 threshold.
// Tracking is now ORDER-INDEPENDENT (max over j), so k_post replication
// no longer depends on the rot order.
__global__ __launch_bounds__(BLK) void k_main(
    const float* __restrict__ labels, const float4* __restrict__ poffs,
    const float4* __restrict__ anchors, const float4* __restrict__ gt,
    Accum* __restrict__ acc, unsigned long long* __restrict__ partial,
    unsigned long long* __restrict__ ghist, int A) {
  __shared__ unsigned long long hist[NB];   // (count<<42) | fixedpoint-sum
  __shared__ unsigned long long sbest[NGTC];
  __shared__ float sgx[NGTC], sgy[NGTC], sgz[NGTC], sgw[NGTC];  // SoA
  __shared__ float sredf[BLK / 64], sredb[BLK / 64];
  __shared__ unsigned sredu[BLK / 64];
  int b = blockIdx.y, t = threadIdx.x;
  for (int i = t; i < NB; i += BLK) hist[i] = 0ull;
  if (t < NGTC) {
    float4 g = gt[b * NGTC + t];
    sgx[t] = g.x; sgy[t] = g.y; sgz[t] = g.z; sgw[t] = g.w;
    sbest[t] = 0ull;
  }
  __syncthreads();

  float psum = 0.f, bsum = 0.f;
  unsigned cnt = 0u;
  int rot = t & 31;
  for (int a0 = blockIdx.x * (2 * BLK) + t; a0 < A; a0 += GX * 2 * BLK) {
    int a1 = a0 + BLK;
    bool v1 = a1 < A;
    float4 av0 = anchors[a0];
    // invalid -> degenerate far box: inter==0 with every gt, area==0
    float4 av1 = v1 ? anchors[a1] : make_float4(2.f, 2.f, 2.f, 2.f);
    v2f ax = {av0.x, av1.x}, ay = {av0.y, av1.y};
    v2f az = {av0.z, av1.z}, aw2 = {av0.w, av1.w};
    v2f area = (az - ax) * (aw2 - ay);
    unsigned na0 = ~(unsigned)a0, na1 = ~(unsigned)a1;
    unsigned um0 = 0u, um1 = 0u;   // (iou_bits & ~31) | (31-j) trackers
#pragma unroll 8
    for (int jj = 0; jj < NGTC; ++jj) {
      int j = (jj + rot) & 31;    // stagger lanes across the 32 sbest slots
      float gx = sgx[j], gy = sgy[j], gz = sgz[j], gw = sgw[j];
      float ga = (gz - gx) * (gw - gy);
      v2f gxv = {gx, gx}, gyv = {gy, gy}, gzv = {gz, gz}, gwv = {gw, gw};
      v2f w = __builtin_elementwise_max(
                  __builtin_elementwise_min(az, gzv) -
                  __builtin_elementwise_max(ax, gxv), (v2f)0.f);
      v2f h = __builtin_elementwise_max(
                  __builtin_elementwise_min(aw2, gwv) -
                  __builtin_elementwise_max(ay, gyv), (v2f)0.f);
      v2f iv = w * h;
      v2f d = area + (v2f){ga, ga} - iv;    // d > 0 always
      v2f iou = {iv.x * __builtin_amdgcn_rcpf(d.x),
                 iv.y * __builtin_amdgcn_rcpf(d.y)};
      unsigned rj = 31u - (unsigned)j;
      unsigned t0k = (__float_as_uint(iou.x) & 0xFFFFFFE0u) | rj;
      unsigned t1k = (__float_as_uint(iou.y) & 0xFFFFFFE0u) | rj;
      um0 = t0k > um0 ? t0k : um0;
      um1 = t1k > um1 ? t1k : um1;
      // fold for the per-GT key (tie -> a0 = smaller index, first-argmax)
      bool take1 = iou.y > iou.x;
      float kiou = take1 ? iou.y : iou.x;
      unsigned naw = take1 ? na1 : na0;
      if (kiou > 0.f)
        atomicMax(&sbest[j],
                  (((unsigned long long)__float_as_uint(kiou)) << 32) | naw);
    }
#pragma unroll
    for (int q = 0; q < 2; ++q) {
      int a = q ? a1 : a0;
      if (q && !v1) break;
      float4 av = q ? av1 : av0;
      unsigned um = q ? um1 : um0;
      bool pos = __uint_as_float(um) > 0.3f;   // low 5 bits = <=31ulp fuzz
      int gid = 31 - (int)(um & 31u);
      float x = labels[(size_t)b * A + a];
      float e = __expf(-fabsf(x));
      float sp = fmaxf(x, 0.f) + __logf(1.f + e);   // softplus = bce(y=0)
      if (pos) {
        cnt++; psum += sp - x;                       // bce(y=1)
        float4 p = poffs[(size_t)b * A + a];
        float4 g = make_float4(sgx[gid], sgy[gid], sgz[gid], sgw[gid]);
        bsum += boxterm(av, g, p);
      } else {
        unsigned bk = __float_as_uint(sp) >> BSH;
        atomicAdd(&hist[bk],
                  (1ull << CNTSH) + (unsigned long long)(unsigned)(sp * FPS + 0.5f));
      }
    }
  }
  __syncthreads();
  if (t < NGTC)
    partial[(size_t)blockIdx.x * (BN * NGTC) + b * NGTC + t] = sbest[t];

  psum = wred_sum_f(psum);
  bsum = wred_sum_f(bsum);
  cnt  = wred_sum_u(cnt);
  int wid = t >> 6, lane = t & 63;
  if (lane == 0) { sredf[wid] = psum; sredb[wid] = bsum; sredu[wid] = cnt; }
  __syncthreads();
  if (t == 0) {
    float ps = 0.f, bs = 0.f; unsigned c = 0;
#pragma unroll
    for (int w2 = 0; w2 < BLK / 64; ++w2) { ps += sredf[w2]; bs += sredb[w2]; c += sredu[w2]; }
    if (c) atomicAdd(&acc->npos[b], c);
    atomicAdd(&acc->pos_sum, ps);
    atomicAdd(&acc->box_sum, bs);
  }
  // merge nonzero buckets: ONE u64 atomic each (packed fields add independently)
  for (int i = t; i < NB; i += BLK) {
    unsigned long long pk = hist[i];
    if (pk) atomicAdd(&ghist[(size_t)b * NB + i], pk);
  }
}

// Parallel epilogue: one block per batch row. Stage+unpack histogram to LDS,
// corrections in LDS, wave-parallel suffix scan; t0 UNCONDITIONALLY does
// writeback+ticket (R10: no data-dependent gating of the ticket — when
// k >= total negatives the reference takes ALL = t0's suffix total).
__global__ __launch_bounds__(BLK) void k_post(
    const float* __restrict__ labels, const float4* __restrict__ poffs,
    const float4* __restrict__ anchors, const float4* __restrict__ gt,
    Accum* __restrict__ acc, const unsigned long long* __restrict__ partial,
    const unsigned long long* __restrict__ ghist,
    float* __restrict__ out, int A, int nbx) {
  __shared__ unsigned hc[NB];
  __shared__ float    hsum[NB];
  __shared__ unsigned long long spart[BLK];
  __shared__ unsigned sa[NGTC];
  __shared__ float sdpos, sdbox;
  __shared__ unsigned sdnp;
  __shared__ unsigned sk;                  // 3 * corrected n_pos
  __shared__ unsigned swtc[BLK / 64];      // wave suffix totals
  __shared__ float    swts[BLK / 64];
  __shared__ float    srow_hard;
  __shared__ int      sdone;
  int b = blockIdx.x, t = threadIdx.x;

  // stage + unpack row histogram (coalesced u64 loads)
  for (int i = t; i < NB; i += BLK) {
    unsigned long long pk = ghist[(size_t)b * NB + i];
    hc[i] = (unsigned)(pk >> CNTSH);
    hsum[i] = (float)(pk & ((1ull << CNTSH) - 1ull)) * (1.f / FPS);
  }
  // parallel partial-key reduce: thread (chunk=t>>5, j=t&31) covers nbx/8 blocks
  {
    int j = t & 31, ch = t >> 5;
    unsigned long long best = 0ull;
    int i0 = ch * (nbx / 8), i1 = i0 + (nbx / 8);
    for (int i = i0; i < i1; ++i) {
      unsigned long long v = partial[(size_t)i * (BN * NGTC) + b * NGTC + j];
      best = v > best ? v : best;
    }
    spart[t] = best;
  }
  if (t == 0) { sdpos = 0.f; sdbox = 0.f; sdnp = 0u; sdone = 0; }
  __syncthreads();
  if (t < NGTC) {
    unsigned long long m = spart[t];
#pragma unroll
    for (int c = 1; c < 8; ++c) {
      unsigned long long v = spart[c * 32 + t];
      m = v > m ? v : m;
    }
    if (m == 0ull) m = 0xFFFFFFFFull;  // no overlap -> anchor 0
    sa[t] = ~(unsigned)(m & 0xFFFFFFFFull);
  }
  __syncthreads();

  // forced-match corrections (threads 0..31, one per gt)
  if (t < NGTC) {
    unsigned a = sa[t];
    bool winner = true;
    for (int j2 = t + 1; j2 < NGTC; ++j2)
      if (sa[j2] == a) { winner = false; break; }  // last j wins
    if (winner) {
      // Replicate k_main's per-anchor tracking EXACTLY (order-independent:
      // same w/h/i/d/rcp-iou DAG, same truncated-key max).
      float4 avx = anchors[a];
      float area_a = (avx.z - avx.x) * (avx.w - avx.y);
      unsigned um = 0u;
      for (int j2 = 0; j2 < NGTC; ++j2) {
        float gx = gt[b * NGTC + j2].x, gy = gt[b * NGTC + j2].y;
        float gz = gt[b * NGTC + j2].z, gw = gt[b * NGTC + j2].w;
        float ga = (gz - gx) * (gw - gy);
        float w = fmaxf(fminf(avx.z, gz) - fmaxf(avx.x, gx), 0.f);
        float h = fmaxf(fminf(avx.w, gw) - fmaxf(avx.y, gy), 0.f);
        float iv = w * h;
        float d = area_a + ga - iv;
        float iou = iv * __builtin_amdgcn_rcpf(d);
        unsigned tk = (__float_as_uint(iou) & 0xFFFFFFE0u) | (31u - (unsigned)j2);
        um = tk > um ? tk : um;
      }
      bool tpos = __uint_as_float(um) > 0.3f;
      int gid = 31 - (int)(um & 31u);
      float4 p4 = poffs[(size_t)b * A + a];
      float newbox = boxterm(avx, gt[b * NGTC + t], p4);
      if (tpos) {
        if (gid != t) {   // box target overridden: swap terms
          float oldbox = boxterm(avx, gt[b * NGTC + gid], p4);
          atomicAdd(&sdbox, newbox - oldbox);
        }
      } else {            // was counted negative: promote to positive
        float x = labels[(size_t)b * A + a];
        float e = __expf(-fabsf(x));
        float sp = fmaxf(x, 0.f) + __logf(1.f + e);
        atomicAdd(&sdnp, 1u);
        atomicAdd(&sdpos, sp - x);
        atomicAdd(&sdbox, newbox);
        unsigned bk = __float_as_uint(sp) >> BSH;
        atomicSub(&hc[bk], 1u);
        atomicAdd(&hsum[bk], -sp);
      }
    }
  }
  __syncthreads();
  if (t == 0) sk = 3u * (acc->npos[b] + sdnp);

  // per-thread chunk sums (4 buckets each) in registers
  unsigned cth = 0; float sth = 0.f;
  {
    int base = t * (NB / BLK);
#pragma unroll
    for (int i = 0; i < NB / BLK; ++i) { cth += hc[base + i]; sth += hsum[base + i]; }
  }
  // wave-internal suffix-inclusive scan (descending index)
  int lane = t & 63, wv = t >> 6;
  unsigned S = cth; float Sf = sth;
#pragma unroll
  for (int off = 1; off < 64; off <<= 1) {
    unsigned cn = __shfl_down(S, off, 64);
    float sn = __shfl_down(Sf, off, 64);
    if (lane + off < 64) { S += cn; Sf += sn; }
  }
  if (lane == 0) { swtc[wv] = S; swts[wv] = Sf; }  // wave totals
  __syncthreads();
#pragma unroll
  for (int w2 = 0; w2 < BLK / 64; ++w2)
    if (w2 > wv) { S += swtc[w2]; Sf += swts[w2]; }
  // S/Sf for thread t = suffix over threads t..255; t0 holds the TOTAL.

  // boundary thread (unique when 1 <= k <= total): compute hard, hand off
  unsigned k = sk;
  if (k > 0u && S >= k && S - cth < k) {
    unsigned cum = S - cth;          // count strictly above my chunk
    float hard = Sf - sth;           // sum strictly above my chunk
    int base = t * (NB / BLK);
    for (int u = NB / BLK - 1; u >= 0; --u) {
      int bk = base + u;
      unsigned c2 = hc[bk];
      if (cum + c2 >= k) {
        unsigned r = k - cum;
        if (c2 && r) {
          float m  = hsum[bk] / (float)c2;
          float lo = __uint_as_float((unsigned)bk << BSH);
          float hi = __uint_as_float((unsigned)(bk + 1) << BSH);
          // uniform-within-bucket model; exact at r==c2
          hard += (float)r * m +
                  (float)r * (float)(c2 - r) * (hi - lo) / (2.f * (float)c2);
        }
        break;
      }
      cum += c2; hard += hsum[bk];
    }
    srow_hard = hard;
    sdone = 1;
  }
  __syncthreads();

  // t0 ALWAYS writes back and tickets (fallback: k >= total -> take all)
  if (t == 0) {
    float hard = sdone ? srow_hard : Sf;   // t0's Sf == total negative sum
    acc->rw_np[b] = k / 3u;
    acc->rw_hard[b] = hard;
    atomicAdd(&acc->pos_sum, sdpos);
    atomicAdd(&acc->box_sum, sdbox);
    __threadfence();
    unsigned tk = atomicAdd(&acc->counter, 1u);
    if (tk == BN - 1u) {       // last row block: final combine
      __threadfence();
      unsigned npt = 0; float hardt = 0.f;
      for (int bb = 0; bb < BN; ++bb) {
        npt += aload_u(&acc->rw_np[bb]);
        hardt += aload_f(&acc->rw_hard[bb]);
      }
      float npf = (float)npt;
      float box = aload_f(&acc->box_sum) / (npf * 4.f);
      float cls = (hardt + aload_f(&acc->pos_sum)) / npf;
      out[0] = box + cls;
      out[1] = box;
      out[2] = cls;
    }
  }
}

extern "C" void kernel_launch(void* const* d_in, const int* in_sizes, int n_in,
                              void* d_out, int out_size, void* d_ws, size_t ws_size,
                              hipStream_t stream) {
  const float*  labels  = (const float*)d_in[0];
  const float4* poffs   = (const float4*)d_in[1];
  const float4* anchors = (const float4*)d_in[2];
  const float4* gt      = (const float4*)d_in[3];
  int A = in_sizes[2] / 4;  // 100000

  char* ws = (char*)d_ws;
  Accum* acc = (Accum*)ws;
  size_t off_gh = (sizeof(Accum) + 255) & ~(size_t)255;
  unsigned long long* ghist = (unsigned long long*)(ws + off_gh);
  size_t off_part = off_gh + (size_t)BN * NB * sizeof(unsigned long long);
  unsigned long long* partial = (unsigned long long*)(ws + off_part);
  // partial (GX*512 u64) is fully written by k_main each call; no memset.

  hipMemsetAsync(ws, 0, off_part, stream);  // Accum(+ticket+rowres) + ghist (~128KB)

  dim3 grid(GX, BN);
  k_main<<<grid, BLK, 0, stream>>>(labels, poffs, anchors, gt, acc, partial,
                                   ghist, A);
  k_post<<<BN, BLK, 0, stream>>>(labels, poffs, anchors, gt, acc, partial,
                                 ghist, (float*)d_out, A, GX);
}